// Round 1
// 292.525 us; speedup vs baseline: 1.0133x; 1.0133x over previous
//
#include <hip/hip_runtime.h>
#include <stdint.h>

// Problem geometry: t is (8, 3, 1024, 1024) fp32.
#define W_IMG 1024u
#define H_IMG 1024u
#define N_ELEM 25165824u            // 8*3*1024*1024

// rotl via single v_alignbit_b32: alignbit(x,x,32-r) = rotl(x,r)
#define ROTL(x, r) __builtin_amdgcn_alignbit((x), (x), 32u - (r))

// jax uniform in [1,2): bitcast((bits>>9)|0x3f800000). Single v_alignbit:
// alignbit(0x7F, b, 9) = (0x7F<<23) | (b>>9).
__device__ __forceinline__ float bits_to_1_2(uint32_t b) {
    return __uint_as_float(__builtin_amdgcn_alignbit(0x7Fu, b, 9u));
}

// 4 pixels per thread along x. 256-thread block = exactly one image row.
// All 16 threefry2x32 chains (4 dirs x 4 pixels) computed ROUND-MAJOR so
// each dependent ARX op has 15 independent insts between it and its
// producer -> per-wave issue is self-sufficient (no reliance on TLP).
__global__ __launch_bounds__(256) void neighbor_noiser_kernel(
        const float* __restrict__ t, float* __restrict__ out) {
    unsigned tid = blockIdx.x * 256u + threadIdx.x;
    unsigned j0 = tid * 4u;                  // first pixel of this thread's quad

    unsigned x4 = j0 & (W_IMG - 1u);         // multiple of 4
    unsigned y  = (j0 >> 10) & (H_IMG - 1u);

    const float4* t4 = (const float4*)t;
    float4 c = t4[j0 >> 2];
    float4 u = t4[(y == 0u            ? j0 : j0 - W_IMG) >> 2];
    float4 d = t4[(y == H_IMG - 1u    ? j0 : j0 + W_IMG) >> 2];
    float lf0 = (x4 == 0u)            ? c.x : t[j0 - 1u];
    float rt3 = (x4 == W_IMG - 4u)    ? c.w : t[j0 + 4u];

    // JAX threefry2x32, key = (0, 42), partitionable mode:
    // counter = (hi=0, lo=i); 32-bit output = out0 ^ out1 (xor-fold).
    // ks = [0, 42, 0x1BD11BF0 (= 0x1BD11BDA ^ 42)].
    // Chain h = dir*4 + px; counter = j0 + px + dir*N; x1_init = ctr + ks[1].
    uint32_t X0[16], X1[16];
    #pragma unroll
    for (int h = 0; h < 16; ++h)
        X1[h] = j0 + (uint32_t)(h & 3) + (uint32_t)(h >> 2) * N_ELEM + 42u;

    const uint32_t k1 = 42u;
    const uint32_t k2 = 0x1BD11BF0u;

    // Round 1 with x0_init = 0: x0 = x1 (register rename, no add needed).
    #define TFR1() { _Pragma("unroll") \
        for (int h = 0; h < 16; ++h) { uint32_t o_ = X1[h]; X0[h] = o_; X1[h] = ROTL(o_, 13u) ^ o_; } }
    #define TFR(r) { _Pragma("unroll") \
        for (int h = 0; h < 16; ++h) { X0[h] += X1[h]; X1[h] = ROTL(X1[h], (r)) ^ X0[h]; } }
    #define INJ(a, b) { _Pragma("unroll") \
        for (int h = 0; h < 16; ++h) { X0[h] += (a); X1[h] += (b); } }
    #define INJ1(b) { _Pragma("unroll") \
        for (int h = 0; h < 16; ++h) { X1[h] += (b); } }

    TFR1()     TFR(15u) TFR(26u) TFR(6u)
    INJ(k1, k2 + 1u)
    TFR(17u) TFR(29u) TFR(16u) TFR(24u)
    INJ(k2, 2u)
    TFR(13u) TFR(15u) TFR(26u) TFR(6u)
    INJ1(k1 + 3u)                            // ks[0] = 0: x0 unchanged
    TFR(17u) TFR(29u) TFR(16u) TFR(24u)
    INJ(k1, k2 + 4u)
    TFR(13u) TFR(15u) TFR(26u) TFR(6u)
    // Final injection folded into the xor-fold: out = (x0 + k2) ^ (x1 + 5).

    float w[16];
    #pragma unroll
    for (int h = 0; h < 16; ++h)
        w[h] = bits_to_1_2((X0[h] + k2) ^ (X1[h] + 5u)) - 1.0f;

    #undef TFR1
    #undef TFR
    #undef INJ
    #undef INJ1

    float ut[4] = {u.x, u.y, u.z, u.w};
    float dt[4] = {d.x, d.y, d.z, d.w};
    float lt[4] = {lf0, c.x, c.y, c.z};
    float rt[4] = {c.y, c.z, c.w, rt3};
    float res[4];
    #pragma unroll
    for (int p = 0; p < 4; ++p) {
        float wu = w[p], wd = w[4 + p], wl = w[8 + p], wr = w[12 + p];
        float num = fmaf(ut[p], wu, fmaf(dt[p], wd, fmaf(lt[p], wl, rt[p] * wr)));
        float den = (wu + wd) + (wl + wr);
        res[p] = __fdividef(num, den);
    }

    float4 o;
    o.x = res[0]; o.y = res[1]; o.z = res[2]; o.w = res[3];
    ((float4*)out)[j0 >> 2] = o;
}

extern "C" void kernel_launch(void* const* d_in, const int* in_sizes, int n_in,
                              void* d_out, int out_size, void* d_ws, size_t ws_size,
                              hipStream_t stream) {
    const float* t = (const float*)d_in[0];
    float* out = (float*)d_out;
    // N = 25165824 elements, 4 per thread, 256 per block -> 24576 blocks exact.
    unsigned blocks = N_ELEM / (4u * 256u);
    neighbor_noiser_kernel<<<dim3(blocks), dim3(256), 0, stream>>>(t, out);
}